// Round 13
// baseline (278.542 us; speedup 1.0000x reference)
//
#include <hip/hip_runtime.h>
#include <hip/hip_bf16.h>

#define D_MODEL 1024
#define NHEAD 16
#define DK 64
#define B_ 4
#define S_ 2048
#define ROWS (B_*S_)          // 8192
#define QKV_N (3*D_MODEL)     // 3072
#define SM_C 0.18033688011112042f   // 0.125 * log2(e), folded into Wq

typedef __attribute__((ext_vector_type(4))) float f32x4;
typedef __attribute__((ext_vector_type(8))) short bf16x8;
typedef unsigned short u16;
typedef unsigned int u32;

__device__ __forceinline__ u16 f2bf(float f) {
    union { float f; u32 u; } x; x.f = f;
    u32 r = x.u + 0x7fffu + ((x.u >> 16) & 1u);
    return (u16)(r >> 16);
}
__device__ __forceinline__ float bf2f(u16 h) {
    union { u32 u; float f; } x; x.u = ((u32)h) << 16;
    return x.f;
}
__device__ __forceinline__ u32 pk2bf(float a, float b) {
    union { __hip_bfloat162 h; u32 u; } c;
    c.h = __float22bfloat162_rn(float2{a, b});
    return c.u;
}

// async global->LDS, 16B per lane.
__device__ __forceinline__ void gload_lds16(const void* g, void* l) {
    __builtin_amdgcn_global_load_lds(
        (const __attribute__((address_space(1))) u32*)g,
        (__attribute__((address_space(3))) u32*)l, 16, 0, 0);
}

// All five f32->bf16 casts + the RoPE cos/sin table in ONE launch
// (region-dispatched by blockIdx).
// Wq is PRE-SCALED by SM_C: Q = x*(C*Wq) = C*(x*Wq) -> softmax needs no
// scale; the uniform 2^T offset cancels in O = (P V)/l and is dropped.
__global__ void cast_all(const float* __restrict__ x,
                         const float* __restrict__ wq, const float* __restrict__ wk,
                         const float* __restrict__ wv, const float* __restrict__ wo,
                         u16* __restrict__ xb, u16* __restrict__ wqkvb, u16* __restrict__ wob,
                         const int* __restrict__ pos, float2* __restrict__ tab) {
    int bi = blockIdx.x;
    if (bi >= 12288) {        // RoPE table: tab[s][i] = {cos,sin}(pos[s]*10000^(-i/32))
        int idx = (bi - 12288) * 256 + (int)threadIdx.x;   // 0..65535
        int s = idx >> 5, i = idx & 31;
        float invf = __expf(-(float)i * 0.2878231366242557f);
        float ang = (float)pos[s] * invf;
        float sn, cs;
        sincosf(ang, &sn, &cs);
        tab[idx] = float2{cs, sn};
        return;
    }
    const float* src; u16* dst; int local; float scale = 1.0f;
    if (bi < 8192)       { src = x;  dst = xb;               local = bi; }
    else if (bi < 9216)  { src = wq; dst = wqkvb;            local = bi - 8192; scale = SM_C; }
    else if (bi < 10240) { src = wk; dst = wqkvb + 1048576;  local = bi - 9216; }
    else if (bi < 11264) { src = wv; dst = wqkvb + 2097152;  local = bi - 10240; }
    else                 { src = wo; dst = wob;              local = bi - 11264; }
    int i = (local * 256 + (int)threadIdx.x) * 4;
    float4 v = *(const float4*)(src + i);
    ushort4 o;
    o.x = f2bf(v.x * scale); o.y = f2bf(v.y * scale);
    o.z = f2bf(v.z * scale); o.w = f2bf(v.w * scale);
    *(ushort4*)(dst + i) = o;
}

// C[m,n] = sum_k A[m,k] * B[n,k];  A:[M,K] bf16, B:[N,K] bf16 (both row-major)
// r10-proven: BK=64, SINGLE 32KB LDS buffer, 2 barriers per K-step, both-
// sides XOR involution byte ^= ((row&7)<<4). Occupancy-optimal; do not grow
// LDS (r8/r9 3-buf and r11 2-buf both lost to this).
// MODE 0: fp32 C.  MODE 1: bf16 C with RoPE fused into the epilogue for
// columns < 2048 (Q,K regions). cos/sin from the precomputed table.
template<int MODE>
__global__ __launch_bounds__(256, 2)
void gemm_bt(const u16* __restrict__ A, const u16* __restrict__ Bm,
             void* __restrict__ Cp, int M, int N, int K,
             const float2* __restrict__ tab) {
    __shared__ u16 As[128 * 64];   // 16 KB, row stride 128 B, XOR-swizzled
    __shared__ u16 Bs[128 * 64];   // 16 KB
    const int tid = threadIdx.x;
    const int lane = tid & 63, wave = tid >> 6;
    const int gx = gridDim.x;
    const int nwg = gx * gridDim.y;
    int lin = blockIdx.y * gx + blockIdx.x;
    int nl = (lin & 7) * (nwg >> 3) + (lin >> 3);
    const int m0 = (nl / gx) * 128, n0 = (nl % gx) * 128;
    const int wm = (wave >> 1) * 64, wn = (wave & 1) * 64;
    const int q4 = lane >> 4, c16 = lane & 15;
    f32x4 acc[4][4] = {};

    const int srow = tid >> 3;                          // 0..31 (+ p*32)
    const int scol = ((tid & 7) ^ (srow & 7)) * 8;      // elements
    const int rsw = (c16 & 7) << 4;

    for (int k0 = 0; k0 < K; k0 += 64) {
        #pragma unroll
        for (int p = 0; p < 4; ++p) {
            gload_lds16(A + (size_t)(m0 + p * 32 + srow) * K + k0 + scol,
                        (char*)As + p * 4096 + tid * 16);
            gload_lds16(Bm + (size_t)(n0 + p * 32 + srow) * K + k0 + scol,
                        (char*)Bs + p * 4096 + tid * 16);
        }
        __syncthreads();
        #pragma unroll
        for (int kk = 0; kk < 2; ++kk) {
            bf16x8 af[4], bf[4];
            #pragma unroll
            for (int mt = 0; mt < 4; ++mt)
                af[mt] = *(const bf16x8*)((const char*)As + (wm + mt * 16 + c16) * 128
                                          + ((kk * 64 + q4 * 16) ^ rsw));
            #pragma unroll
            for (int nt = 0; nt < 4; ++nt)
                bf[nt] = *(const bf16x8*)((const char*)Bs + (wn + nt * 16 + c16) * 128
                                          + ((kk * 64 + q4 * 16) ^ rsw));
            #pragma unroll
            for (int mt = 0; mt < 4; ++mt)
                #pragma unroll
                for (int nt = 0; nt < 4; ++nt)
                    acc[mt][nt] = __builtin_amdgcn_mfma_f32_16x16x32_bf16(af[mt], bf[nt], acc[mt][nt], 0, 0, 0);
        }
        __syncthreads();
    }

    const bool doRope = (MODE == 1) && (n0 < 2048);   // block-uniform
    int ti[4];
    #pragma unroll
    for (int nt = 0; nt < 4; ++nt)
        ti[nt] = ((n0 + wn + nt * 16 + c16) >> 1) & 31;

    #pragma unroll
    for (int mt = 0; mt < 4; ++mt)
        #pragma unroll
        for (int r = 0; r < 4; ++r) {
            const int row = m0 + wm + mt * 16 + q4 * 4 + r;
            float sn[4], cs[4];
            if (doRope) {
                const float2* trow = tab + (size_t)(row & (S_ - 1)) * 32;
                #pragma unroll
                for (int nt = 0; nt < 4; ++nt) {
                    float2 t = trow[ti[nt]];
                    cs[nt] = t.x; sn[nt] = t.y;
                }
            }
            #pragma unroll
            for (int nt = 0; nt < 4; ++nt) {
                const int col = n0 + wn + nt * 16 + c16;
                float v = acc[mt][nt][r];
                if (doRope) {
                    const float partner = __shfl_xor(v, 1, 64);
                    v = (c16 & 1) ? __builtin_fmaf(sn[nt], partner, cs[nt] * v)
                                  : __builtin_fmaf(cs[nt], v, -sn[nt] * partner);
                }
                if (MODE == 1) ((u16*)Cp)[(size_t)row * N + col] = f2bf(v);
                else           ((float*)Cp)[(size_t)row * N + col] = v;
            }
        }
}

// Softmax, no scale/offset: Q pre-scaled by C at cast time; uniform 2^T
// offset cancels in O = (P V)/l. p = exp2(s'), s' <= ~46 -> p <= 8e13 (fp32
// safe); masked entries exp2(-1e30) = 0. Per-lane l partials. Writes the
// P strip and reads the PV A-fragment back before returning (so a following
// call may safely reuse the same strip -- same-wave DS program order).
__device__ __forceinline__ void softmax_p(
    f32x4 (&sf)[4], u16* __restrict__ Psw, float& l_i,
    int qrow0, int kt, bool diag, int c16, int q4, bf16x8 (&pf)[2]) {
    if (diag) {
        const int qg = qrow0 + c16;
        #pragma unroll
        for (int nt = 0; nt < 4; ++nt)
            #pragma unroll
            for (int r = 0; r < 4; ++r) {
                int kg = kt * 64 + nt * 16 + q4 * 4 + r;
                if (kg > qg) sf[nt][r] = -1e30f;
            }
    }
    float rs = 0.f;
    #pragma unroll
    for (int nt = 0; nt < 4; ++nt) {
        float p0 = exp2f(sf[nt][0]);
        float p1 = exp2f(sf[nt][1]);
        float p2 = exp2f(sf[nt][2]);
        float p3 = exp2f(sf[nt][3]);
        rs += (p0 + p1) + (p2 + p3);
        uint2 w; w.x = pk2bf(p0, p1); w.y = pk2bf(p2, p3);
        *(uint2*)&Psw[c16 * 72 + nt * 16 + q4 * 4] = w;   // P[qrow][key]
    }
    l_i += rs;
    pf[0] = *(const bf16x8*)&Psw[c16 * 72 + q4 * 8];
    pf[1] = *(const bf16x8*)&Psw[c16 * 72 + 32 + q4 * 8];
}

// Flash attention v2: 512-thread blocks = 2 wave-quads sharing one K/V
// staging stream (r10's lesson applied to attn: per bh, staged tiles/barriers
// drop 331 -> 200, per-thread staging halves, occupancy 12 -> 16 waves/CU).
// Quad q (waves 4q..4q+3) processes pair (tA,tB) = (2g+q, 31-2g-q); both
// quads' work sums to 33 processes each -> perfectly balanced. Per-wave inner
// code (merged-strip QK/softmax/PV) identical to the proven pair kernel; Ps
// is shared per wave between its A and B strips (r2-r6 proven WAR pattern).
// Barrier is outside all activity guards -> uniform.
__global__ __launch_bounds__(512, 4)
void attn_kernel(const u16* __restrict__ QKV, u16* __restrict__ O) {
    __shared__ u16 Kt[2][64 * 64];    // 16 KB
    __shared__ u16 Vt[2][64 * 72];    // 18 KB
    __shared__ u16 Ps[8][16 * 72];    // 18 KB, per wave (A/B share)
    __shared__ float aS[8][16];
    const int tid = threadIdx.x, lane = tid & 63, wave = tid >> 6;  // 0..7
    const int wq = wave & 3, quad = wave >> 2;
    const int q4 = lane >> 4, c16 = lane & 15;
    // XCD-chunked: 512 blocks, 8 per bh; consecutive nl share bh.
    int lin = blockIdx.y * 8 + blockIdx.x;
    int nl = (lin & 7) * 64 + (lin >> 3);
    const int g = nl & 7;
    const int bh = nl >> 3;
    const int b = bh >> 4, h = bh & 15;
    const size_t rowbase = (size_t)b * S_ * QKV_N;

    const int tA = 2 * g + quad;            // 0..15
    const int tB = 31 - 2 * g - quad;       // 16..31, tA < tB always
    const int tBmax = 31 - 2 * g;           // block-uniform loop bound

    // K staging: 512 threads x 16B = one 64x64 K tile; row = tid>>3.
    const int kr = tid >> 3;
    const int kcsw = ((tid & 7) ^ (kr & 7)) * 8;   // pre-swizzled source col
    const u16* ksrc0 = QKV + rowbase + (size_t)kr * QKV_N + D_MODEL + h * 64 + kcsw;
    const int ksw = (c16 & 7) << 4;
    const int koff0 = (q4 * 16) ^ ksw;
    const int koff1 = (64 + q4 * 16) ^ ksw;

    // V staging: thread covers keys {2kp,2kp+1} x 4 d's -> packed b32
    const int kp = tid & 31, dg = tid >> 5;        // dg 0..15
    const u16* vbase = QKV + rowbase + (size_t)(2 * kp) * QKV_N + 2 * D_MODEL + h * 64 + dg * 4;

    bf16x8 qfA[2], qfB[2];
    {
        const u16* qa = QKV + rowbase + (size_t)(tA * 64 + wq * 16 + c16) * QKV_N + h * 64 + q4 * 8;
        qfA[0] = *(const bf16x8*)qa;
        qfA[1] = *(const bf16x8*)(qa + 32);
        const u16* qb = QKV + rowbase + (size_t)(tB * 64 + wq * 16 + c16) * QKV_N + h * 64 + q4 * 8;
        qfB[0] = *(const bf16x8*)qb;
        qfB[1] = *(const bf16x8*)(qb + 32);
    }
    f32x4 ofA[4] = {}, ofB[4] = {};
    float lA = 0.f, lB = 0.f;
    const int qrowA = tA * 64 + wq * 16;
    const int qrowB = tB * 64 + wq * 16;

    // prologue: stage tile 0 into buffer 0
    gload_lds16(ksrc0, (char*)Kt[0] + tid * 16);
    ushort4 va = *(const ushort4*)vbase, vb = *(const ushort4*)(vbase + QKV_N);
    {
        const u16* pa = (const u16*)&va; const u16* pb = (const u16*)&vb;
        #pragma unroll
        for (int j = 0; j < 4; ++j) {
            u32 w = ((u32)pa[j]) | (((u32)pb[j]) << 16);
            *(u32*)&Vt[0][(dg * 4 + j) * 72 + 2 * kp] = w;
        }
    }
    __syncthreads();

    int bb = 0;
    for (int kt = 0; kt <= tBmax; ++kt) {
        const bool more = kt < tBmax;          // block-uniform
        const bool aAct = kt <= tA;            // quad-uniform
        const bool bAct = kt <= tB;            // quad-uniform
        if (more) {    // prefetch next tile: K via DMA, V to regs
            gload_lds16(ksrc0 + (size_t)(kt + 1) * 64 * QKV_N, (char*)Kt[bb ^ 1] + tid * 16);
            const u16* vp_ = vbase + (size_t)(kt + 1) * 64 * QKV_N;
            va = *(const ushort4*)vp_;  vb = *(const ushort4*)(vp_ + QKV_N);
        }

        f32x4 sfA[4] = {}, sfB[4] = {};
        const char* Kb = (const char*)Kt[bb];
        __builtin_amdgcn_s_setprio(1);
        if (aAct) {
            #pragma unroll
            for (int nt = 0; nt < 4; ++nt) {
                bf16x8 kf0 = *(const bf16x8*)(Kb + nt * 2048 + c16 * 128 + koff0);
                bf16x8 kf1 = *(const bf16x8*)(Kb + nt * 2048 + c16 * 128 + koff1);
                sfB[nt] = __builtin_amdgcn_mfma_f32_16x16x32_bf16(kf0, qfB[0], sfB[nt], 0, 0, 0);
                sfB[nt] = __builtin_amdgcn_mfma_f32_16x16x32_bf16(kf1, qfB[1], sfB[nt], 0, 0, 0);
                sfA[nt] = __builtin_amdgcn_mfma_f32_16x16x32_bf16(kf0, qfA[0], sfA[nt], 0, 0, 0);
                sfA[nt] = __builtin_amdgcn_mfma_f32_16x16x32_bf16(kf1, qfA[1], sfA[nt], 0, 0, 0);
            }
        } else if (bAct) {
            #pragma unroll
            for (int nt = 0; nt < 4; ++nt) {
                bf16x8 kf0 = *(const bf16x8*)(Kb + nt * 2048 + c16 * 128 + koff0);
                bf16x8 kf1 = *(const bf16x8*)(Kb + nt * 2048 + c16 * 128 + koff1);
                sfB[nt] = __builtin_amdgcn_mfma_f32_16x16x32_bf16(kf0, qfB[0], sfB[nt], 0, 0, 0);
                sfB[nt] = __builtin_amdgcn_mfma_f32_16x16x32_bf16(kf1, qfB[1], sfB[nt], 0, 0, 0);
            }
        }
        __builtin_amdgcn_s_setprio(0);

        // softmax A then B sharing Ps[wave] (pf extracted inside before reuse)
        bf16x8 pfA[2], pfB[2];
        if (aAct) softmax_p(sfA, Ps[wave], lA, qrowA, kt, kt == tA, c16, q4, pfA);
        if (bAct) softmax_p(sfB, Ps[wave], lB, qrowB, kt, kt == tB, c16, q4, pfB);

        if (more) {    // commit V mid-iteration
            const u16* pa = (const u16*)&va; const u16* pb = (const u16*)&vb;
            #pragma unroll
            for (int j = 0; j < 4; ++j) {
                u32 w = ((u32)pa[j]) | (((u32)pb[j]) << 16);
                *(u32*)&Vt[bb ^ 1][(dg * 4 + j) * 72 + 2 * kp] = w;
            }
        }

        const u16* Vb = Vt[bb];
        __builtin_amdgcn_s_setprio(1);
        if (aAct) {
            #pragma unroll
            for (int kk = 0; kk < 2; ++kk)
                #pragma unroll
                for (int nt = 0; nt < 4; ++nt) {
                    bf16x8 vf = *(const bf16x8*)&Vb[(nt * 16 + c16) * 72 + kk * 32 + q4 * 8];
                    ofB[nt] = __builtin_amdgcn_mfma_f32_16x16x32_bf16(pfB[kk], vf, ofB[nt], 0, 0, 0);
                    ofA[nt] = __builtin_amdgcn_mfma_f32_16x16x32_bf16(pfA[kk], vf, ofA[nt], 0, 0, 0);
                }
        } else if (bAct) {
            #pragma unroll
            for (int kk = 0; kk < 2; ++kk)
                #pragma unroll
                for (int nt = 0; nt < 4; ++nt) {
                    bf16x8 vf = *(const bf16x8*)&Vb[(nt * 16 + c16) * 72 + kk * 32 + q4 * 8];
                    ofB[nt] = __builtin_amdgcn_mfma_f32_16x16x32_bf16(pfB[kk], vf, ofB[nt], 0, 0, 0);
                }
        }
        __builtin_amdgcn_s_setprio(0);

        __syncthreads();
        bb ^= 1;
    }

    // epilogue: cross-lane l reduce, redistribute, write O (per wave)
    lA += __shfl_xor(lA, 16, 64); lA += __shfl_xor(lA, 32, 64);
    lB += __shfl_xor(lB, 16, 64); lB += __shfl_xor(lB, 32, 64);
    if (q4 == 0) aS[wave][c16] = lA;
    f32x4 lv = *(const f32x4*)&aS[wave][q4 * 4];
    #pragma unroll
    for (int r = 0; r < 4; ++r) {
        float inv = 1.0f / lv[r];
        int row = b * S_ + tA * 64 + wq * 16 + q4 * 4 + r;
        #pragma unroll
        for (int nt = 0; nt < 4; ++nt)
            O[(size_t)row * D_MODEL + h * 64 + nt * 16 + c16] = f2bf(ofA[nt][r] * inv);
    }
    if (q4 == 0) aS[wave][c16] = lB;
    f32x4 lv2 = *(const f32x4*)&aS[wave][q4 * 4];
    #pragma unroll
    for (int r = 0; r < 4; ++r) {
        float inv = 1.0f / lv2[r];
        int row = b * S_ + tB * 64 + wq * 16 + q4 * 4 + r;
        #pragma unroll
        for (int nt = 0; nt < 4; ++nt)
            O[(size_t)row * D_MODEL + h * 64 + nt * 16 + c16] = f2bf(ofB[nt][r] * inv);
    }
}

extern "C" void kernel_launch(void* const* d_in, const int* in_sizes, int n_in,
                              void* d_out, int out_size, void* d_ws, size_t ws_size,
                              hipStream_t stream) {
    const float* x  = (const float*)d_in[0];
    const int*   tp = (const int*)d_in[1];
    const float* Wq = (const float*)d_in[2];
    const float* Wk = (const float*)d_in[3];
    const float* Wv = (const float*)d_in[4];
    const float* Wo = (const float*)d_in[5];
    float* out = (float*)d_out;

    char* ws = (char*)d_ws;
    u16* xb    = (u16*)(ws);                 // 16,777,216 B
    u16* Wqkvb = (u16*)(ws + 16777216);      //  6,291,456 B
    u16* Wob   = (u16*)(ws + 23068672);      //  2,097,152 B
    u16* QKV   = (u16*)(ws + 25165824);      // 50,331,648 B
    u16* Ob    = (u16*)(ws + 75497472);      // 16,777,216 B  (total 92,274,688 B)
    // RoPE table lives in the first 512 KB of the Ob region: it is consumed
    // only by the qkv GEMM epilogue, which completes before attn writes Ob.
    float2* tab = (float2*)(ws + 75497472);

    cast_all<<<dim3(12544), dim3(256), 0, stream>>>(x, Wq, Wk, Wv, Wo,
                                                    xb, Wqkvb, Wob, tp, tab);

    // qkv projection with fused RoPE in the epilogue.
    gemm_bt<1><<<dim3(QKV_N / 128, ROWS / 128), dim3(256), 0, stream>>>(
        xb, Wqkvb, (void*)QKV, ROWS, QKV_N, D_MODEL, tab);

    attn_kernel<<<dim3(8, B_ * NHEAD), dim3(512), 0, stream>>>(QKV, Ob);

    gemm_bt<0><<<dim3(D_MODEL / 128, ROWS / 128), dim3(256), 0, stream>>>(
        Ob, Wob, (void*)out, ROWS, D_MODEL, D_MODEL, nullptr);
}